// Round 1
// 166.835 us; speedup vs baseline: 1.0221x; 1.0221x over previous
//
#include <hip/hip_runtime.h>

#define DIM_ 1024
#define NH_ 16
#define HD_ 64
#define B_ 2
#define S_ 2048
#define M_ (B_ * S_)      // 4096
#define NQKV_ (3 * DIM_)  // 3072

typedef __attribute__((ext_vector_type(8))) __bf16 bf16x8;
typedef __attribute__((ext_vector_type(4))) __bf16 bf16x4;
typedef __attribute__((ext_vector_type(4))) float f32x4;

__device__ __forceinline__ void gl_lds16(const void* g, void* l) {
  __builtin_amdgcn_global_load_lds(
      (__attribute__((address_space(1))) void*)const_cast<void*>(g),
      (__attribute__((address_space(3))) void*)l, 16, 0, 0);
}

// ---------------- fused cast fp32 -> bf16 for x, qkv_w, proj_w ----------------
#define N4_X 1048576   // 4096*1024/4
#define N4_W1 786432   // 3072*1024/4
#define N4_W2 262144   // 1024*1024/4
__global__ __launch_bounds__(256) void cast_all(const float* __restrict__ x,
                                                const float* __restrict__ w1,
                                                const float* __restrict__ w2,
                                                __bf16* __restrict__ xb,
                                                __bf16* __restrict__ w1b,
                                                __bf16* __restrict__ w2b) {
  int i = blockIdx.x * 256 + threadIdx.x;
  const int stride = gridDim.x * 256;
  for (; i < N4_X + N4_W1 + N4_W2; i += stride) {
    const float4* src;
    bf16x4* dst;
    int j;
    if (i < N4_X) { src = (const float4*)x; dst = (bf16x4*)xb; j = i; }
    else if (i < N4_X + N4_W1) { src = (const float4*)w1; dst = (bf16x4*)w1b; j = i - N4_X; }
    else { src = (const float4*)w2; dst = (bf16x4*)w2b; j = i - (N4_X + N4_W1); }
    float4 v = src[j];
    bf16x4 o;
    o[0] = (__bf16)v.x; o[1] = (__bf16)v.y; o[2] = (__bf16)v.z; o[3] = (__bf16)v.w;
    dst[j] = o;
  }
}

// ---------------- BMx128 bf16 MFMA GEMM, BK=64, B-transposed, 512 threads ----------------
// (unchanged)
template <int MODE, int BM>
__global__ __launch_bounds__(512, 4) void gemm_bt(const __bf16* __restrict__ A,
                                                  const __bf16* __restrict__ Bw,
                                                  const float* __restrict__ bias,
                                                  __bf16* __restrict__ Qp, __bf16* __restrict__ Kp,
                                                  __bf16* __restrict__ Vt,
                                                  float* __restrict__ Cout) {
  constexpr int KD = 1024;
  constexpr int BN = 128;
  constexpr int MT = BM / 64;          // m-tiles (of 16 rows) per wave
  constexpr int NC = (BM + BN) / 64;   // 16B chunks staged per thread
  __shared__ __bf16 As[BM * 64];
  __shared__ __bf16 Bs[BN * 64];
  const int tid = threadIdx.x;
  const int lane = tid & 63;
  const int wave = tid >> 6;  // 0..7
  const int quad = lane >> 4;
  const int r16 = lane & 15;
  const int wm = wave >> 1;   // 0..3
  const int wn = wave & 1;    // 0..1
  const int m0 = blockIdx.y * BM;
  const int n0 = blockIdx.x * BN;

  const f32x4 fz = {0.f, 0.f, 0.f, 0.f};
  f32x4 acc[MT][4];
#pragma unroll
  for (int i = 0; i < MT; ++i)
#pragma unroll
    for (int j = 0; j < 4; ++j) acc[i][j] = fz;

  const __bf16* gp[NC];
  __bf16* lp[NC];
#pragma unroll
  for (int i = 0; i < NC; ++i) {
    const int c = tid + i * 512;
    if (c < BM * 8) {
      const int r = c >> 3, cc = c & 7;
      gp[i] = A + (size_t)(m0 + r) * KD + ((cc ^ (r & 7)) * 8);
      lp[i] = &As[c * 8];
    } else {
      const int c2 = c - BM * 8;
      const int r = c2 >> 3, cc = c2 & 7;
      gp[i] = Bw + (size_t)(n0 + r) * KD + ((cc ^ (r & 7)) * 8);
      lp[i] = &Bs[c2 * 8];
    }
  }

  for (int kt = 0; kt < KD / 64; ++kt) {
    __syncthreads();
#pragma unroll
    for (int i = 0; i < NC; ++i) { gl_lds16(gp[i], lp[i]); gp[i] += 64; }
    __syncthreads();

#pragma unroll
    for (int sub = 0; sub < 2; ++sub) {
      const int ch = ((sub * 4 + quad) ^ (r16 & 7)) * 8;
      bf16x8 af[MT], bfr[4];
#pragma unroll
      for (int mt = 0; mt < MT; ++mt)
        af[mt] = *(const bf16x8*)&As[(wm * MT * 16 + mt * 16 + r16) * 64 + ch];
#pragma unroll
      for (int nt = 0; nt < 4; ++nt)
        bfr[nt] = *(const bf16x8*)&Bs[(wn * 64 + nt * 16 + r16) * 64 + ch];
#pragma unroll
      for (int mt = 0; mt < MT; ++mt)
#pragma unroll
        for (int nt = 0; nt < 4; ++nt)
          acc[mt][nt] =
              __builtin_amdgcn_mfma_f32_16x16x32_bf16(af[mt], bfr[nt], acc[mt][nt], 0, 0, 0);
    }
  }

  if (MODE == 0) {
#pragma unroll
    for (int nt = 0; nt < 4; ++nt) {
      const int n = n0 + wn * 64 + nt * 16 + r16;
      const int sel = n >> 10;  // wave-uniform (n range is 64-aligned, 64-wide)
      const int h = (n >> 6) & 15;
      const int dh = n & 63;
      const float bs = bias[n];
      if (sel == 2) {
#pragma unroll
        for (int mt = 0; mt < MT; ++mt) {
          const int m = m0 + wm * MT * 16 + mt * 16 + quad * 4;
          const int b = m >> 11;
          const int s = m & 2047;
          const int slot = (s & ~31) | (((s >> 2) & 3) << 3) | (((s >> 4) & 1) << 2);
          bf16x4 ov;
#pragma unroll
          for (int r = 0; r < 4; ++r) ov[r] = (__bf16)(acc[mt][nt][r] + bs);
          *(bf16x4*)&Vt[((size_t)((b * NH_ + h) * HD_ + dh)) * S_ + slot] = ov;
        }
      } else {
        __bf16* dst = (sel == 0) ? Qp : Kp;
        const float mul = (sel == 0) ? 0.18033688011112042f : 1.0f;
#pragma unroll
        for (int mt = 0; mt < MT; ++mt) {
#pragma unroll
          for (int r = 0; r < 4; ++r) {
            const int m = m0 + wm * MT * 16 + mt * 16 + quad * 4 + r;
            const int b = m >> 11;
            const int s = m & 2047;
            dst[((size_t)((b * NH_ + h) * S_ + s)) * HD_ + dh] =
                (__bf16)((acc[mt][nt][r] + bs) * mul);
          }
        }
      }
    }
  } else {
#pragma unroll
    for (int nt = 0; nt < 4; ++nt) {
      const int n = n0 + wn * 64 + nt * 16 + r16;
      const float bs = bias[n];
#pragma unroll
      for (int mt = 0; mt < MT; ++mt) {
#pragma unroll
        for (int r = 0; r < 4; ++r) {
          const int m = m0 + wm * MT * 16 + mt * 16 + quad * 4 + r;
          Cout[(size_t)m * DIM_ + n] = acc[mt][nt][r] + bs;
        }
      }
    }
  }
}

// ---------------- flash attention, S^T form, 4 waves x 32q, double-buffered ----------------
// LDS-BW fix: each wave now serves 32 q-rows (two 16-row groups sharing every K/V
// fragment read) -> LDS read traffic per unit work halved vs the 8-wave/16q version.
// 256 threads, 64KB LDS -> 2 blocks/CU (staggered barriers). Per 32-key chunk:
// 4 K ds_reads -> 8 QK MFMAs -> 16 exp2 -> 4 V ds_reads -> 8 PV MFMAs.
// XCD-bijective swizzle: all 16 q-blocks of one bh on one XCD (4 bh * 512KB = 2MB < L2).
__global__ __launch_bounds__(256, 2) void attn(const __bf16* __restrict__ Qp,
                                               const __bf16* __restrict__ Kp,
                                               const __bf16* __restrict__ Vtp,
                                               __bf16* __restrict__ ctx) {
  __shared__ __bf16 Ks[2][128 * 64];
  __shared__ __bf16 Vs[2][64 * 128];
  const int tid = threadIdx.x;
  const int lane = tid & 63;
  const int wave = tid >> 6;  // 0..3
  const int quad = lane >> 4;
  const int r16 = lane & 15;

  // XCD swizzle: w = y*16+x; xcd = w&7; slot = w>>3; bh = xcd + 8*(slot>>4); qblk = slot&15.
  const int w = blockIdx.y * 16 + blockIdx.x;  // 0..511
  const int bh = (w & 7) + (((w >> 3) >> 4) << 3);
  const int q0 = ((w >> 3) & 15) * 128;

  // Q fragments for both 16-row groups (rows wave*32 + g*16 + r16)
  const __bf16* qg0 = Qp + ((size_t)bh * S_ + (q0 + wave * 32 + r16)) * HD_;
  const __bf16* qg1 = qg0 + 16 * HD_;
  const bf16x8 qa0 = *(const bf16x8*)(qg0 + quad * 8);
  const bf16x8 qa1 = *(const bf16x8*)(qg0 + 32 + quad * 8);
  const bf16x8 qc0 = *(const bf16x8*)(qg1 + quad * 8);
  const bf16x8 qc1 = *(const bf16x8*)(qg1 + 32 + quad * 8);

  const f32x4 fz = {0.f, 0.f, 0.f, 0.f};
  f32x4 o0[4], o1[4];
#pragma unroll
  for (int d = 0; d < 4; ++d) { o0[d] = fz; o1[d] = fz; }
  float ls0 = 0.f, ls1 = 0.f;

  // staging: 256 threads, 4 K-chunks + 4 V-chunks (16B) per thread per tile
  const __bf16* gk[4];
  const __bf16* gv[4];
  int lofs[4];
#pragma unroll
  for (int i = 0; i < 4; ++i) {
    const int c = tid + i * 256;
    const int kr = c >> 3, kc = c & 7;
    gk[i] = Kp + ((size_t)bh * S_ + kr) * HD_ + ((kc ^ (kr & 7)) * 8);
    const int vr = c >> 4, vc = c & 15;
    gv[i] = Vtp + ((size_t)bh * HD_ + vr) * S_ + ((vc ^ (vr & 15)) * 8);
    lofs[i] = c * 8;
  }

#pragma unroll
  for (int i = 0; i < 4; ++i) {
    gl_lds16(gk[i], &Ks[0][lofs[i]]); gk[i] += 128 * HD_;
    gl_lds16(gv[i], &Vs[0][lofs[i]]); gv[i] += 128;
  }

  for (int kt = 0; kt < S_ / 128; ++kt) {
    const int cb = kt & 1;
    __syncthreads();
    if (kt + 1 < S_ / 128) {
#pragma unroll
      for (int i = 0; i < 4; ++i) {
        gl_lds16(gk[i], &Ks[cb ^ 1][lofs[i]]); gk[i] += 128 * HD_;
        gl_lds16(gv[i], &Vs[cb ^ 1][lofs[i]]); gv[i] += 128;
      }
    }

#pragma unroll
    for (int ks = 0; ks < 4; ++ks) {
      // --- QK^T for 32 keys x both q-groups; K frags reused across groups ---
      const int row0 = ks * 32 + r16;
      const int row1 = row0 + 16;
      const int xa = (quad ^ (r16 & 7)) * 8;
      const int xb = ((4 + quad) ^ (r16 & 7)) * 8;
      const bf16x8 k00 = *(const bf16x8*)&Ks[cb][row0 * 64 + xa];
      const bf16x8 k01 = *(const bf16x8*)&Ks[cb][row0 * 64 + xb];
      const bf16x8 k10 = *(const bf16x8*)&Ks[cb][row1 * 64 + xa];
      const bf16x8 k11 = *(const bf16x8*)&Ks[cb][row1 * 64 + xb];
      f32x4 t00 = fz, t01 = fz, t10 = fz, t11 = fz;
      t00 = __builtin_amdgcn_mfma_f32_16x16x32_bf16(k00, qa0, t00, 0, 0, 0);
      t00 = __builtin_amdgcn_mfma_f32_16x16x32_bf16(k01, qa1, t00, 0, 0, 0);
      t01 = __builtin_amdgcn_mfma_f32_16x16x32_bf16(k10, qa0, t01, 0, 0, 0);
      t01 = __builtin_amdgcn_mfma_f32_16x16x32_bf16(k11, qa1, t01, 0, 0, 0);
      t10 = __builtin_amdgcn_mfma_f32_16x16x32_bf16(k00, qc0, t10, 0, 0, 0);
      t10 = __builtin_amdgcn_mfma_f32_16x16x32_bf16(k01, qc1, t10, 0, 0, 0);
      t11 = __builtin_amdgcn_mfma_f32_16x16x32_bf16(k10, qc0, t11, 0, 0, 0);
      t11 = __builtin_amdgcn_mfma_f32_16x16x32_bf16(k11, qc1, t11, 0, 0, 0);

      // --- softmax numerator: p = 2^s (Q pre-scaled by 0.125*log2e) ---
      bf16x8 pf0, pf1;
#pragma unroll
      for (int r = 0; r < 4; ++r) {
        const float p00 = __builtin_amdgcn_exp2f(t00[r]);
        const float p01 = __builtin_amdgcn_exp2f(t01[r]);
        const float p10 = __builtin_amdgcn_exp2f(t10[r]);
        const float p11 = __builtin_amdgcn_exp2f(t11[r]);
        ls0 += p00 + p01;
        ls1 += p10 + p11;
        pf0[r] = (__bf16)p00; pf0[4 + r] = (__bf16)p01;
        pf1[r] = (__bf16)p10; pf1[4 + r] = (__bf16)p11;
      }

      // --- O^T += V^T P^T; V frags reused across groups ---
#pragma unroll
      for (int dt = 0; dt < 4; ++dt) {
        const int row = dt * 16 + r16;
        const bf16x8 va = *(const bf16x8*)&Vs[cb][row * 128 + (((4 * ks + quad) ^ r16) * 8)];
        o0[dt] = __builtin_amdgcn_mfma_f32_16x16x32_bf16(va, pf0, o0[dt], 0, 0, 0);
        o1[dt] = __builtin_amdgcn_mfma_f32_16x16x32_bf16(va, pf1, o1[dt], 0, 0, 0);
      }
    }
  }

  ls0 += __shfl_xor(ls0, 16);
  ls0 += __shfl_xor(ls0, 32);
  ls1 += __shfl_xor(ls1, 16);
  ls1 += __shfl_xor(ls1, 32);
  const float inv0 = 1.0f / ls0;
  const float inv1 = 1.0f / ls1;
  const int b = bh >> 4, h = bh & 15;
  const int s0 = q0 + wave * 32 + r16;
  const int s1 = s0 + 16;
#pragma unroll
  for (int dt = 0; dt < 4; ++dt) {
    bf16x4 ov0, ov1;
#pragma unroll
    for (int r = 0; r < 4; ++r) {
      ov0[r] = (__bf16)(o0[dt][r] * inv0);
      ov1[r] = (__bf16)(o1[dt][r] * inv1);
    }
    *(bf16x4*)&ctx[((size_t)(b * S_ + s0)) * DIM_ + h * 64 + dt * 16 + quad * 4] = ov0;
    *(bf16x4*)&ctx[((size_t)(b * S_ + s1)) * DIM_ + h * 64 + dt * 16 + quad * 4] = ov1;
  }
}

// ---------------- host launch ----------------
extern "C" void kernel_launch(void* const* d_in, const int* in_sizes, int n_in, void* d_out,
                              int out_size, void* d_ws, size_t ws_size, hipStream_t stream) {
  const float* x = (const float*)d_in[0];
  const float* qkv_w = (const float*)d_in[1];
  const float* qkv_b = (const float*)d_in[2];
  const float* proj_w = (const float*)d_in[3];
  const float* proj_b = (const float*)d_in[4];
  float* out = (float*)d_out;

  char* ws = (char*)d_ws;
  __bf16* Xb = (__bf16*)(ws);              // 8,388,608
  __bf16* Wb = (__bf16*)(ws + 8388608);    // 6,291,456
  __bf16* Pb = (__bf16*)(ws + 14680064);   // 2,097,152
  __bf16* Qp = (__bf16*)(ws + 16777216);   // 8,388,608 (pre-scaled by 0.125*log2e)
  __bf16* Kp = (__bf16*)(ws + 25165824);   // 8,388,608
  __bf16* Vt = (__bf16*)(ws + 33554432);   // 8,388,608 (transposed + key-permuted)
  __bf16* Cx = (__bf16*)(ws + 41943040);   // 8,388,608 -> ends 50,331,648

  cast_all<<<2048, 256, 0, stream>>>(x, qkv_w, proj_w, Xb, Wb, Pb);
  gemm_bt<0, 128><<<dim3(NQKV_ / 128, M_ / 128), 512, 0, stream>>>(Xb, Wb, qkv_b, Qp, Kp, Vt,
                                                                   nullptr);
  attn<<<dim3(S_ / 128, 32), 256, 0, stream>>>(Qp, Kp, Vt, Cx);
  gemm_bt<1, 64><<<dim3(DIM_ / 128, M_ / 64), 512, 0, stream>>>(Cx, Pb, proj_b, nullptr, nullptr,
                                                                nullptr, out);
}

// Round 2
// 163.923 us; speedup vs baseline: 1.0403x; 1.0178x over previous
//
#include <hip/hip_runtime.h>

#define DIM_ 1024
#define NH_ 16
#define HD_ 64
#define B_ 2
#define S_ 2048
#define M_ (B_ * S_)      // 4096
#define NQKV_ (3 * DIM_)  // 3072

typedef __attribute__((ext_vector_type(8))) __bf16 bf16x8;
typedef __attribute__((ext_vector_type(4))) __bf16 bf16x4;
typedef __attribute__((ext_vector_type(4))) float f32x4;

__device__ __forceinline__ void gl_lds16(const void* g, void* l) {
  __builtin_amdgcn_global_load_lds(
      (__attribute__((address_space(1))) void*)const_cast<void*>(g),
      (__attribute__((address_space(3))) void*)l, 16, 0, 0);
}

// ---------------- fused cast fp32 -> bf16 for x, qkv_w, proj_w ----------------
#define N4_X 1048576   // 4096*1024/4
#define N4_W1 786432   // 3072*1024/4
#define N4_W2 262144   // 1024*1024/4
__global__ __launch_bounds__(256) void cast_all(const float* __restrict__ x,
                                                const float* __restrict__ w1,
                                                const float* __restrict__ w2,
                                                __bf16* __restrict__ xb,
                                                __bf16* __restrict__ w1b,
                                                __bf16* __restrict__ w2b) {
  int i = blockIdx.x * 256 + threadIdx.x;
  const int stride = gridDim.x * 256;
  for (; i < N4_X + N4_W1 + N4_W2; i += stride) {
    const float4* src;
    bf16x4* dst;
    int j;
    if (i < N4_X) { src = (const float4*)x; dst = (bf16x4*)xb; j = i; }
    else if (i < N4_X + N4_W1) { src = (const float4*)w1; dst = (bf16x4*)w1b; j = i - N4_X; }
    else { src = (const float4*)w2; dst = (bf16x4*)w2b; j = i - (N4_X + N4_W1); }
    float4 v = src[j];
    bf16x4 o;
    o[0] = (__bf16)v.x; o[1] = (__bf16)v.y; o[2] = (__bf16)v.z; o[3] = (__bf16)v.w;
    dst[j] = o;
  }
}

// ---------------- BMx128 bf16 MFMA GEMM, BK=64, B-transposed, 512 threads ----------------
// (unchanged)
template <int MODE, int BM>
__global__ __launch_bounds__(512, 4) void gemm_bt(const __bf16* __restrict__ A,
                                                  const __bf16* __restrict__ Bw,
                                                  const float* __restrict__ bias,
                                                  __bf16* __restrict__ Qp, __bf16* __restrict__ Kp,
                                                  __bf16* __restrict__ Vt,
                                                  float* __restrict__ Cout) {
  constexpr int KD = 1024;
  constexpr int BN = 128;
  constexpr int MT = BM / 64;          // m-tiles (of 16 rows) per wave
  constexpr int NC = (BM + BN) / 64;   // 16B chunks staged per thread
  __shared__ __bf16 As[BM * 64];
  __shared__ __bf16 Bs[BN * 64];
  const int tid = threadIdx.x;
  const int lane = tid & 63;
  const int wave = tid >> 6;  // 0..7
  const int quad = lane >> 4;
  const int r16 = lane & 15;
  const int wm = wave >> 1;   // 0..3
  const int wn = wave & 1;    // 0..1
  const int m0 = blockIdx.y * BM;
  const int n0 = blockIdx.x * BN;

  const f32x4 fz = {0.f, 0.f, 0.f, 0.f};
  f32x4 acc[MT][4];
#pragma unroll
  for (int i = 0; i < MT; ++i)
#pragma unroll
    for (int j = 0; j < 4; ++j) acc[i][j] = fz;

  const __bf16* gp[NC];
  __bf16* lp[NC];
#pragma unroll
  for (int i = 0; i < NC; ++i) {
    const int c = tid + i * 512;
    if (c < BM * 8) {
      const int r = c >> 3, cc = c & 7;
      gp[i] = A + (size_t)(m0 + r) * KD + ((cc ^ (r & 7)) * 8);
      lp[i] = &As[c * 8];
    } else {
      const int c2 = c - BM * 8;
      const int r = c2 >> 3, cc = c2 & 7;
      gp[i] = Bw + (size_t)(n0 + r) * KD + ((cc ^ (r & 7)) * 8);
      lp[i] = &Bs[c2 * 8];
    }
  }

  for (int kt = 0; kt < KD / 64; ++kt) {
    __syncthreads();
#pragma unroll
    for (int i = 0; i < NC; ++i) { gl_lds16(gp[i], lp[i]); gp[i] += 64; }
    __syncthreads();

#pragma unroll
    for (int sub = 0; sub < 2; ++sub) {
      const int ch = ((sub * 4 + quad) ^ (r16 & 7)) * 8;
      bf16x8 af[MT], bfr[4];
#pragma unroll
      for (int mt = 0; mt < MT; ++mt)
        af[mt] = *(const bf16x8*)&As[(wm * MT * 16 + mt * 16 + r16) * 64 + ch];
#pragma unroll
      for (int nt = 0; nt < 4; ++nt)
        bfr[nt] = *(const bf16x8*)&Bs[(wn * 64 + nt * 16 + r16) * 64 + ch];
#pragma unroll
      for (int mt = 0; mt < MT; ++mt)
#pragma unroll
        for (int nt = 0; nt < 4; ++nt)
          acc[mt][nt] =
              __builtin_amdgcn_mfma_f32_16x16x32_bf16(af[mt], bfr[nt], acc[mt][nt], 0, 0, 0);
    }
  }

  if (MODE == 0) {
#pragma unroll
    for (int nt = 0; nt < 4; ++nt) {
      const int n = n0 + wn * 64 + nt * 16 + r16;
      const int sel = n >> 10;  // wave-uniform (n range is 64-aligned, 64-wide)
      const int h = (n >> 6) & 15;
      const int dh = n & 63;
      const float bs = bias[n];
      if (sel == 2) {
#pragma unroll
        for (int mt = 0; mt < MT; ++mt) {
          const int m = m0 + wm * MT * 16 + mt * 16 + quad * 4;
          const int b = m >> 11;
          const int s = m & 2047;
          const int slot = (s & ~31) | (((s >> 2) & 3) << 3) | (((s >> 4) & 1) << 2);
          bf16x4 ov;
#pragma unroll
          for (int r = 0; r < 4; ++r) ov[r] = (__bf16)(acc[mt][nt][r] + bs);
          *(bf16x4*)&Vt[((size_t)((b * NH_ + h) * HD_ + dh)) * S_ + slot] = ov;
        }
      } else {
        __bf16* dst = (sel == 0) ? Qp : Kp;
        const float mul = (sel == 0) ? 0.18033688011112042f : 1.0f;
#pragma unroll
        for (int mt = 0; mt < MT; ++mt) {
#pragma unroll
          for (int r = 0; r < 4; ++r) {
            const int m = m0 + wm * MT * 16 + mt * 16 + quad * 4 + r;
            const int b = m >> 11;
            const int s = m & 2047;
            dst[((size_t)((b * NH_ + h) * S_ + s)) * HD_ + dh] =
                (__bf16)((acc[mt][nt][r] + bs) * mul);
          }
        }
      }
    }
  } else {
#pragma unroll
    for (int nt = 0; nt < 4; ++nt) {
      const int n = n0 + wn * 64 + nt * 16 + r16;
      const float bs = bias[n];
#pragma unroll
      for (int mt = 0; mt < MT; ++mt) {
#pragma unroll
        for (int r = 0; r < 4; ++r) {
          const int m = m0 + wm * MT * 16 + mt * 16 + quad * 4 + r;
          Cout[(size_t)m * DIM_ + n] = acc[mt][nt][r] + bs;
        }
      }
    }
  }
}

// ---------------- flash attention, in-block KV-split, 8 waves, G=2 (32q/wave) ----------------
// Waves 0-3 process keys [0,1024), waves 4-7 keys [1024,2048) for the SAME 128 q-rows.
// Total waves doubles (4096 -> 16 waves/CU = 4/SIMD) with LDS read traffic unchanged
// (traffic is invariant under KV-split; only G changes it). KVBLK=64 double-buffered per
// half: LDS = 2buf x 2half x (8KiB K + 8KiB V) = 64 KiB -> 2 blocks/CU.
// Partials combined IN-BLOCK via LDS exchange (stride 36 f32: 16B-aligned, 2-way banks).
// XCD-bijective swizzle unchanged (K/V stay L2-resident: FETCH was 12 MB).
__global__ __launch_bounds__(512, 4) void attn(const __bf16* __restrict__ Qp,
                                               const __bf16* __restrict__ Kp,
                                               const __bf16* __restrict__ Vtp,
                                               __bf16* __restrict__ ctx) {
  __shared__ alignas(16) char smem[65536];
  __bf16* KsB = (__bf16*)smem;            // [2 buf][2 half][64*64]
  __bf16* VsB = (__bf16*)(smem + 32768);  // [2 buf][2 half][64*64]
  const int tid = threadIdx.x;
  const int lane = tid & 63;
  const int wave = tid >> 6;  // 0..7
  const int quad = lane >> 4;
  const int r16 = lane & 15;
  const int kh = wave >> 2;   // kv half: 0 -> keys [0,1024), 1 -> [1024,2048)
  const int ww = wave & 3;    // q sub-tile within the 128-row block

  // XCD swizzle: w = y*16+x; xcd = w&7; slot = w>>3; bh = xcd + 8*(slot>>4); qblk = slot&15.
  const int w = blockIdx.y * 16 + blockIdx.x;  // 0..511
  const int bh = (w & 7) + (((w >> 3) >> 4) << 3);
  const int q0 = ((w >> 3) & 15) * 128;

  // Q fragments for both 16-row groups (rows q0 + ww*32 + g*16 + r16)
  const __bf16* qg0 = Qp + ((size_t)bh * S_ + (q0 + ww * 32 + r16)) * HD_;
  const __bf16* qg1 = qg0 + 16 * HD_;
  const bf16x8 qa0 = *(const bf16x8*)(qg0 + quad * 8);
  const bf16x8 qa1 = *(const bf16x8*)(qg0 + 32 + quad * 8);
  const bf16x8 qc0 = *(const bf16x8*)(qg1 + quad * 8);
  const bf16x8 qc1 = *(const bf16x8*)(qg1 + 32 + quad * 8);

  const f32x4 fz = {0.f, 0.f, 0.f, 0.f};
  f32x4 o0[4], o1[4];
#pragma unroll
  for (int d = 0; d < 4; ++d) { o0[d] = fz; o1[d] = fz; }
  float ls0 = 0.f, ls1 = 0.f;

  // staging: 2048 16B chunks per tile (K: both halves 1024 chunks, V: both halves 1024).
  // chunk c (0..1023): half = c>>9, row r = (c>>3)&63, col chunk cc = c&7, XOR-swizzled src.
  const __bf16* gk[2];
  const __bf16* gv[2];
  int lk[2], lv[2];
#pragma unroll
  for (int i = 0; i < 2; ++i) {
    const int c = tid + i * 512;        // 0..1023
    const int half = c >> 9;
    const int r = (c >> 3) & 63;
    const int cc = c & 7;
    gk[i] = Kp + ((size_t)bh * S_ + half * 1024 + r) * HD_ + ((cc ^ (r & 7)) * 8);
    lk[i] = c * 8;
    gv[i] = Vtp + ((size_t)bh * HD_ + r) * S_ + half * 1024 + ((cc ^ (r & 7)) * 8);
    lv[i] = c * 8;
  }

  // prefetch tile 0 into buf 0
#pragma unroll
  for (int i = 0; i < 2; ++i) {
    gl_lds16(gk[i], KsB + lk[i]); gk[i] += 64 * HD_;
    gl_lds16(gv[i], VsB + lv[i]); gv[i] += 64;
  }

  constexpr int NT = 1024 / 64;  // 16 tiles per half
  for (int kt = 0; kt < NT; ++kt) {
    const int cb = kt & 1;
    __syncthreads();
    if (kt + 1 < NT) {
#pragma unroll
      for (int i = 0; i < 2; ++i) {
        gl_lds16(gk[i], KsB + (cb ^ 1) * 8192 + lk[i]); gk[i] += 64 * HD_;
        gl_lds16(gv[i], VsB + (cb ^ 1) * 8192 + lv[i]); gv[i] += 64;
      }
    }

    const __bf16* Kt = KsB + cb * 8192 + kh * 4096;
    const __bf16* Vt2 = VsB + cb * 8192 + kh * 4096;

#pragma unroll
    for (int ks = 0; ks < 2; ++ks) {
      // --- QK^T for 32 keys x both q-groups; K frags reused across groups ---
      const int row0 = ks * 32 + r16;
      const int row1 = row0 + 16;
      const int xa = (quad ^ (r16 & 7)) * 8;
      const int xb = ((4 + quad) ^ (r16 & 7)) * 8;
      const bf16x8 k00 = *(const bf16x8*)&Kt[row0 * 64 + xa];
      const bf16x8 k01 = *(const bf16x8*)&Kt[row0 * 64 + xb];
      const bf16x8 k10 = *(const bf16x8*)&Kt[row1 * 64 + xa];
      const bf16x8 k11 = *(const bf16x8*)&Kt[row1 * 64 + xb];
      f32x4 t00 = fz, t01 = fz, t10 = fz, t11 = fz;
      t00 = __builtin_amdgcn_mfma_f32_16x16x32_bf16(k00, qa0, t00, 0, 0, 0);
      t00 = __builtin_amdgcn_mfma_f32_16x16x32_bf16(k01, qa1, t00, 0, 0, 0);
      t01 = __builtin_amdgcn_mfma_f32_16x16x32_bf16(k10, qa0, t01, 0, 0, 0);
      t01 = __builtin_amdgcn_mfma_f32_16x16x32_bf16(k11, qa1, t01, 0, 0, 0);
      t10 = __builtin_amdgcn_mfma_f32_16x16x32_bf16(k00, qc0, t10, 0, 0, 0);
      t10 = __builtin_amdgcn_mfma_f32_16x16x32_bf16(k01, qc1, t10, 0, 0, 0);
      t11 = __builtin_amdgcn_mfma_f32_16x16x32_bf16(k10, qc0, t11, 0, 0, 0);
      t11 = __builtin_amdgcn_mfma_f32_16x16x32_bf16(k11, qc1, t11, 0, 0, 0);

      // --- softmax numerator: p = 2^s (Q pre-scaled by 0.125*log2e) ---
      bf16x8 pf0, pf1;
#pragma unroll
      for (int r = 0; r < 4; ++r) {
        const float p00 = __builtin_amdgcn_exp2f(t00[r]);
        const float p01 = __builtin_amdgcn_exp2f(t01[r]);
        const float p10 = __builtin_amdgcn_exp2f(t10[r]);
        const float p11 = __builtin_amdgcn_exp2f(t11[r]);
        ls0 += p00 + p01;
        ls1 += p10 + p11;
        pf0[r] = (__bf16)p00; pf0[4 + r] = (__bf16)p01;
        pf1[r] = (__bf16)p10; pf1[4 + r] = (__bf16)p11;
      }

      // --- O^T += V^T P^T; V frags reused across groups ---
#pragma unroll
      for (int dt = 0; dt < 4; ++dt) {
        const int row = dt * 16 + r16;
        const bf16x8 va = *(const bf16x8*)&Vt2[row * 64 + (((4 * ks + quad) ^ (r16 & 7)) * 8)];
        o0[dt] = __builtin_amdgcn_mfma_f32_16x16x32_bf16(va, pf0, o0[dt], 0, 0, 0);
        o1[dt] = __builtin_amdgcn_mfma_f32_16x16x32_bf16(va, pf1, o1[dt], 0, 0, 0);
      }
    }
  }

  // lane-reduce lsum over quads (keys are spread across quad = lane bits 4-5)
  ls0 += __shfl_xor(ls0, 16);
  ls0 += __shfl_xor(ls0, 32);
  ls1 += __shfl_xor(ls1, 16);
  ls1 += __shfl_xor(ls1, 32);

  // --- in-block combine of the two KV halves via LDS ---
  __syncthreads();  // all tile reads done; safe to reuse smem
  float* xfer = (float*)smem;
  float* p = xfer + (ww * 64 + lane) * 36;  // 36 f32 = 144 B: 16B-aligned, 2-way banks
  if (kh) {
    *(f32x4*)(p + 0) = o0[0];  *(f32x4*)(p + 4) = o0[1];
    *(f32x4*)(p + 8) = o0[2];  *(f32x4*)(p + 12) = o0[3];
    *(f32x4*)(p + 16) = o1[0]; *(f32x4*)(p + 20) = o1[1];
    *(f32x4*)(p + 24) = o1[2]; *(f32x4*)(p + 28) = o1[3];
    p[32] = ls0; p[33] = ls1;
  }
  __syncthreads();
  if (!kh) {
    o0[0] += *(const f32x4*)(p + 0);  o0[1] += *(const f32x4*)(p + 4);
    o0[2] += *(const f32x4*)(p + 8);  o0[3] += *(const f32x4*)(p + 12);
    o1[0] += *(const f32x4*)(p + 16); o1[1] += *(const f32x4*)(p + 20);
    o1[2] += *(const f32x4*)(p + 24); o1[3] += *(const f32x4*)(p + 28);
    ls0 += p[32]; ls1 += p[33];
    const float inv0 = 1.0f / ls0;
    const float inv1 = 1.0f / ls1;
    const int b = bh >> 4, h = bh & 15;
    const int s0 = q0 + ww * 32 + r16;
    const int s1 = s0 + 16;
#pragma unroll
    for (int dt = 0; dt < 4; ++dt) {
      bf16x4 ov0, ov1;
#pragma unroll
      for (int r = 0; r < 4; ++r) {
        ov0[r] = (__bf16)(o0[dt][r] * inv0);
        ov1[r] = (__bf16)(o1[dt][r] * inv1);
      }
      *(bf16x4*)&ctx[((size_t)(b * S_ + s0)) * DIM_ + h * 64 + dt * 16 + quad * 4] = ov0;
      *(bf16x4*)&ctx[((size_t)(b * S_ + s1)) * DIM_ + h * 64 + dt * 16 + quad * 4] = ov1;
    }
  }
}

// ---------------- host launch ----------------
extern "C" void kernel_launch(void* const* d_in, const int* in_sizes, int n_in, void* d_out,
                              int out_size, void* d_ws, size_t ws_size, hipStream_t stream) {
  const float* x = (const float*)d_in[0];
  const float* qkv_w = (const float*)d_in[1];
  const float* qkv_b = (const float*)d_in[2];
  const float* proj_w = (const float*)d_in[3];
  const float* proj_b = (const float*)d_in[4];
  float* out = (float*)d_out;

  char* ws = (char*)d_ws;
  __bf16* Xb = (__bf16*)(ws);              // 8,388,608
  __bf16* Wb = (__bf16*)(ws + 8388608);    // 6,291,456
  __bf16* Pb = (__bf16*)(ws + 14680064);   // 2,097,152
  __bf16* Qp = (__bf16*)(ws + 16777216);   // 8,388,608 (pre-scaled by 0.125*log2e)
  __bf16* Kp = (__bf16*)(ws + 25165824);   // 8,388,608
  __bf16* Vt = (__bf16*)(ws + 33554432);   // 8,388,608 (transposed + key-permuted)
  __bf16* Cx = (__bf16*)(ws + 41943040);   // 8,388,608 -> ends 50,331,648

  cast_all<<<2048, 256, 0, stream>>>(x, qkv_w, proj_w, Xb, Wb, Pb);
  gemm_bt<0, 128><<<dim3(NQKV_ / 128, M_ / 128), 512, 0, stream>>>(Xb, Wb, qkv_b, Qp, Kp, Vt,
                                                                   nullptr);
  attn<<<dim3(S_ / 128, 32), 512, 0, stream>>>(Qp, Kp, Vt, Cx);
  gemm_bt<1, 64><<<dim3(DIM_ / 128, M_ / 64), 512, 0, stream>>>(Cx, Pb, proj_b, nullptr, nullptr,
                                                                nullptr, out);
}